// Round 10
// baseline (158.122 us; speedup 1.0000x reference)
//
#include <hip/hip_runtime.h>
#include <hip/hip_bf16.h>
#include <cstdint>

#define EPS 1e-5f
#define PATH_COEFF 0.04419417382415922f   // 1/sqrt(512)
#define CG110     0.5773502691896258f     // 1/sqrt(3)

typedef __bf16 v8bf __attribute__((ext_vector_type(8)));
typedef _Float16 v8h __attribute__((ext_vector_type(8)));
typedef float  v4f  __attribute__((ext_vector_type(4)));
typedef _Float16 v4h __attribute__((ext_vector_type(4)));

static __device__ __forceinline__ unsigned short f2bf(float x){
    unsigned int u = __builtin_bit_cast(unsigned int, x);
    u += 0x7fffu + ((u >> 16) & 1u);      // RNE
    return (unsigned short)(u >> 16);
}
static __device__ __forceinline__ unsigned short f2h(float x){
    return __builtin_bit_cast(unsigned short, (_Float16)x);
}

// ---------------------------------------------------------------------------
// K0: fused prep. blocks [0,260): we_w2/we_b2 -> Vth (fp16) frag-major;
// [260,264): om_w1 -> w1t bf16 transpose; [264,776): per-row prep, wave/row
// (Q2h fp16 frag-major, Htp fp16 [k][n] with k=64 bias row, k=65..67 zero).
// ---------------------------------------------------------------------------
__global__ __launch_bounds__(256)
void k_pre(const float* __restrict__ w2, const float* __restrict__ b2,
           unsigned short* __restrict__ Vth,
           const float* __restrict__ om_w1, unsigned short* __restrict__ w1t,
           const float* __restrict__ x, const float* __restrict__ lng,
           const float* __restrict__ lnb, const float* __restrict__ we_w1,
           unsigned short* __restrict__ Q2h, unsigned short* __restrict__ Htp, int N)
{
    __shared__ __align__(16) unsigned short tile[32][128];   // 8 KB
    int b = blockIdx.x;
    int t = threadIdx.x;

    if (b < 260){
        // ---- convV: Vth[k][ps16][quad4][w128][8p] fp16 ----
        int k    = b >> 2;
        int slab = b & 3;
        const float* srcbase = (k < 64) ? (w2 + (size_t)k * 65536) : b2;
        for (int chunk = 0; chunk < 4; ++chunk){
            int pbase = slab*128 + chunk*32;
            #pragma unroll
            for (int i = 0; i < 4; ++i){
                int g = t + 256*i;
                int ploc = g >> 5, c4 = g & 31;
                const float4 v = *(const float4*)(srcbase + (size_t)(pbase + ploc)*128 + c4*4);
                unsigned int w0 = (unsigned)f2h(v.x) | ((unsigned)f2h(v.y) << 16);
                unsigned int w1 = (unsigned)f2h(v.z) | ((unsigned)f2h(v.w) << 16);
                *(uint2*)&tile[ploc][c4*4] = make_uint2(w0, w1);
            }
            __syncthreads();
            int w = t & 127, h = t >> 7;
            int ps = slab*4 + chunk;
            unsigned int words[8];
            #pragma unroll
            for (int g2 = 0; g2 < 8; ++g2)
                words[g2] = (unsigned)tile[h*16 + g2*2][w] | ((unsigned)tile[h*16 + g2*2 + 1][w] << 16);
            unsigned short* dq0 = Vth + (((size_t)(k*16 + ps)*4 + 2*h    )*128 + w)*8;
            unsigned short* dq1 = Vth + (((size_t)(k*16 + ps)*4 + 2*h + 1)*128 + w)*8;
            *(uint4*)dq0 = make_uint4(words[0], words[1], words[2], words[3]);
            *(uint4*)dq1 = make_uint4(words[4], words[5], words[6], words[7]);
            __syncthreads();
        }
    } else if (b < 264){
        // ---- convW: w1t[j512][w128] bf16 = om_w1[w][j] ----
        int j0 = (b - 260) * 128;
        for (int chunk = 0; chunk < 4; ++chunk){
            #pragma unroll
            for (int i = 0; i < 4; ++i){
                int g = t + 256*i;
                int wloc = g >> 5, c4 = g & 31;
                int w = chunk*32 + wloc;
                const float4 v = *(const float4*)(om_w1 + (size_t)w*512 + j0 + c4*4);
                unsigned int a = (unsigned)f2bf(v.x) | ((unsigned)f2bf(v.y) << 16);
                unsigned int bb = (unsigned)f2bf(v.z) | ((unsigned)f2bf(v.w) << 16);
                *(uint2*)&tile[wloc][c4*4] = make_uint2(a, bb);
            }
            __syncthreads();
            int jl = t & 127, h = t >> 7;
            unsigned int words[8];
            #pragma unroll
            for (int g2 = 0; g2 < 8; ++g2)
                words[g2] = (unsigned)tile[h*16 + g2*2][jl] | ((unsigned)tile[h*16 + g2*2 + 1][jl] << 16);
            unsigned short* dst = w1t + (size_t)(j0 + jl)*128 + chunk*32 + h*16;
            *(uint4*)dst       = make_uint4(words[0], words[1], words[2], words[3]);
            *(uint4*)(dst + 8) = make_uint4(words[4], words[5], words[6], words[7]);
            __syncthreads();
        }
    } else {
        // ---- prep: wave per row, 4 rows/block ----
        int wv = t >> 6, lane = t & 63;
        int row = (b - 264)*4 + wv;
        const float* xr = x + (size_t)row * 64;
        float f[16]; float mu = 0.f;
        #pragma unroll
        for (int u = 0; u < 16; ++u){ f[u] = xr[u]; mu += f[u]; }
        mu *= (1.f/16.f);
        float var = 0.f;
        #pragma unroll
        for (int u = 0; u < 16; ++u){ float d = f[u] - mu; var += d*d; }
        var *= (1.f/16.f);
        float inv = rsqrtf(var + EPS);
        float lnf[16];
        #pragma unroll
        for (int u = 0; u < 16; ++u) lnf[u] = (f[u]-mu)*inv*lng[u] + lnb[u];
        float h1 = 0.f;
        #pragma unroll
        for (int u = 0; u < 16; ++u) h1 += lnf[u] * we_w1[u*64 + lane];
        float h = h1 / (1.f + expf(-h1));
        _Float16* hq = (_Float16*)Htp;
        hq[(size_t)lane * N + row] = (_Float16)h;
        if (lane == 0) hq[(size_t)64 * N + row] = (_Float16)1.f;
        if (lane >= 1 && lane <= 3) hq[(size_t)(64 + lane) * N + row] = (_Float16)0.f;

        union { unsigned short qs[8]; uint4 v; } qu;
        #pragma unroll
        for (int j = 0; j < 8; ++j){
            int p = lane*8 + j;
            float q;
            if (p < 256){
                int u = p >> 4, v = p & 15;
                q = PATH_COEFF * f[u] * f[v];
            } else {
                int pp = p - 256;
                int u = pp >> 4, v = pp & 15;
                const float* ya = xr + 16 + u*3;
                const float* yb = xr + 16 + v*3;
                q = (PATH_COEFF * CG110) * (ya[0]*yb[0] + ya[1]*yb[1] + ya[2]*yb[2]);
            }
            qu.qs[j] = f2h(q);
        }
        int rb = row >> 6, r64 = row & 63;
        int ps = lane >> 2, quad4 = lane & 3;
        *(uint4*)(Q2h + (((size_t)(rb*16 + ps)*4 + quad4)*64 + r64)*8) = qu.v;
    }
}

// ---------------------------------------------------------------------------
// K1: partial[c][n][w] (fp16) = sum_{k in [4c,4c+4)} sum_p (H[n,k]Q[n,p])V[k,p,w]
// H folded into the A-operand: A'[n,p] = H[n,k]*Q[n,p] via packed fp16 mul
// (per-lane row-aligned with MFMA A layout). Single master acc (64 VGPR),
// C=4 k-chunk: 4 A-loads amortized over 64 MFMA/ps. k padded to 68 with
// Htp=0 (zero-scaled A nullifies unwritten V; 0xAA poison is finite fp16).
// Grid 32 mb x 17 c = 544 x 128 thr, lb(128,3). Direct global loads.
// ---------------------------------------------------------------------------
__global__ __launch_bounds__(128, 3)
void k_main(const unsigned short* __restrict__ Q2h, const unsigned short* __restrict__ Vth,
            const unsigned short* __restrict__ Htp, unsigned short* __restrict__ partial, int N)
{
    __shared__ __align__(16) unsigned short Es[2][16*66];   // 4.2 KB
    int c  = blockIdx.x % 17;
    int mb = blockIdx.x / 17;
    int k0 = c*4;

    int tid  = threadIdx.x;
    int lane = tid & 63, wv = tid >> 6;
    int quad = lane >> 4, l16 = lane & 15;
    int rowbase = mb * 64;
    int wbase = wv * 64;

    // H scalars: row (rowbase + m*16 + l16), k0+k
    const _Float16* hq = (const _Float16*)Htp;
    _Float16 hh[4][4];
    #pragma unroll
    for (int k = 0; k < 4; ++k)
      #pragma unroll
      for (int m = 0; m < 4; ++m)
        hh[k][m] = hq[(size_t)(k0 + k)*N + rowbase + m*16 + l16];

    const unsigned short* aroot = Q2h + (size_t)mb*32768 + quad*512  + l16*8;
    const unsigned short* broot = Vth + (size_t)k0*65536 + quad*1024 + (wbase + l16)*8;

    v4f acc[4][4];
    #pragma unroll
    for (int m=0;m<4;++m)
      #pragma unroll
      for (int n=0;n<4;++n)
        #pragma unroll
        for (int r=0;r<4;++r) acc[m][n][r] = 0.f;

    for (int ps = 0; ps < 16; ++ps){
        const unsigned short* ap = aroot + ps*2048;
        v8h aq[4];
        #pragma unroll
        for (int m=0;m<4;++m) aq[m] = *(const v8h*)(ap + m*128);
        #pragma unroll
        for (int k = 0; k < 4; ++k){
            const unsigned short* bp = broot + k*65536 + ps*4096;
            v8h bb[4];
            #pragma unroll
            for (int n=0;n<4;++n) bb[n] = *(const v8h*)(bp + n*128);
            #pragma unroll
            for (int m=0;m<4;++m){
                v8h am = aq[m] * hh[k][m];       // v_pk_mul_f16 x4
                #pragma unroll
                for (int n=0;n<4;++n)
                    acc[m][n] = __builtin_amdgcn_mfma_f32_16x16x32_f16(am, bb[n], acc[m][n], 0, 0, 0);
            }
        }
    }

    // epilogue: fp16, wave-private LDS transpose, dense 128B-row stores
    unsigned short* Esw = Es[wv];
    unsigned short* gp = partial + (size_t)c*N*128 + (size_t)rowbase*128 + wbase;
    #pragma unroll
    for (int m = 0; m < 4; ++m){
        #pragma unroll
        for (int n = 0; n < 4; ++n)
          #pragma unroll
          for (int r = 0; r < 4; ++r)
            Esw[(quad*4 + r)*66 + n*16 + l16] = f2h(acc[m][n][r]);
        #pragma unroll
        for (int jj = 0; jj < 2; ++jj){
            int idx = lane*2 + jj;
            int rr = idx >> 3, cc = idx & 7;
            *(uint4*)(gp + (size_t)(m*16 + rr)*128 + cc*8) = *(const uint4*)(Esw + rr*66 + cc*8);
        }
    }
}

// ---------------------------------------------------------------------------
// K2: reduce 17 fp16 slices + LayerNorm(128) -> lnf bf16. 4 rows/block,
// 128 thr: thread owns (row = t>>5, w = (t&31)*4). Dense 8B loads.
// ---------------------------------------------------------------------------
__global__ __launch_bounds__(128)
void k_red(const unsigned short* __restrict__ partial, const float* __restrict__ g,
           const float* __restrict__ b, unsigned short* __restrict__ lnf, int N)
{
    int t = threadIdx.x;
    int row0 = blockIdx.x * 4;
    int rl = t >> 5, w = (t & 31)*4;
    int row = row0 + rl;

    const unsigned short* p0 = partial + (size_t)row*128 + w;
    float s0=0.f, s1=0.f, s2=0.f, s3=0.f;
    #pragma unroll
    for (int sl = 0; sl < 17; ++sl){
        v4h v = *(const v4h*)(p0 + (size_t)sl*N*128);
        s0 += (float)v[0]; s1 += (float)v[1]; s2 += (float)v[2]; s3 += (float)v[3];
    }
    float sum = s0+s1+s2+s3;
    float sq  = s0*s0+s1*s1+s2*s2+s3*s3;
    #pragma unroll
    for (int off=16; off>0; off>>=1){
        sum += __shfl_xor(sum, off, 32);
        sq  += __shfl_xor(sq,  off, 32);
    }
    float mu  = sum * (1.f/128.f);
    float var = sq * (1.f/128.f) - mu*mu;
    float inv = rsqrtf(var + EPS);
    unsigned short o[4];
    o[0] = f2bf((s0-mu)*inv*g[w+0] + b[w+0]);
    o[1] = f2bf((s1-mu)*inv*g[w+1] + b[w+1]);
    o[2] = f2bf((s2-mu)*inv*g[w+2] + b[w+2]);
    o[3] = f2bf((s3-mu)*inv*g[w+3] + b[w+3]);
    *(uint2*)(lnf + (size_t)row*128 + w) = *(uint2*)o;
}

// ---------------------------------------------------------------------------
// K3: out[n] = silu(lnf @ om_w1) @ om_w2 + om_b2. 32 blocks x 64 rows,
// 4 waves, wave wv owns j-range [wv*128, +128): 4x8 MFMA tiles. LDS reduce.
// ---------------------------------------------------------------------------
__global__ __launch_bounds__(256)
void k_mlp2(const unsigned short* __restrict__ lnf, const unsigned short* __restrict__ w1t,
            const float* __restrict__ w2, const float* __restrict__ b2,
            float* __restrict__ out, int N)
{
    __shared__ float red2[4][64];
    int tid = threadIdx.x, lane = tid & 63, wv = tid >> 6;
    int quad = lane >> 4, l16 = lane & 15;
    int rowbase = blockIdx.x * 64;
    int jbase = wv * 128;

    v4f acc[4][8];
    #pragma unroll
    for (int m=0;m<4;++m)
      #pragma unroll
      for (int n=0;n<8;++n)
        #pragma unroll
        for (int r=0;r<4;++r) acc[m][n][r] = 0.f;

    #pragma unroll
    for (int ps = 0; ps < 4; ++ps){
        v8bf a[4], bb[8];
        #pragma unroll
        for (int m=0;m<4;++m)
            a[m]  = *(const v8bf*)(lnf + (size_t)(rowbase + m*16 + l16)*128 + ps*32 + quad*8);
        #pragma unroll
        for (int n=0;n<8;++n)
            bb[n] = *(const v8bf*)(w1t + (size_t)(jbase + n*16 + l16)*128 + ps*32 + quad*8);
        #pragma unroll
        for (int m=0;m<4;++m)
          #pragma unroll
          for (int n=0;n<8;++n)
            acc[m][n] = __builtin_amdgcn_mfma_f32_16x16x32_bf16(a[m], bb[n], acc[m][n], 0, 0, 0);
    }

    float w2v[8];
    #pragma unroll
    for (int n=0;n<8;++n) w2v[n] = w2[jbase + n*16 + l16];

    #pragma unroll
    for (int m=0;m<4;++m){
        #pragma unroll
        for (int r=0;r<4;++r){
            float s = 0.f;
            #pragma unroll
            for (int n=0;n<8;++n){
                float v = acc[m][n][r];
                s += (v / (1.f + expf(-v))) * w2v[n];
            }
            #pragma unroll
            for (int off=8; off>0; off>>=1) s += __shfl_xor(s, off, 16);
            if (l16 == 0) red2[wv][m*16 + quad*4 + r] = s;
        }
    }
    __syncthreads();
    if (tid < 64)
        out[rowbase + tid] = red2[0][tid] + red2[1][tid] + red2[2][tid] + red2[3][tid] + b2[0];
}

// ---------------------------------------------------------------------------
extern "C" void kernel_launch(void* const* d_in, const int* in_sizes, int n_in,
                              void* d_out, int out_size, void* d_ws, size_t ws_size,
                              hipStream_t stream)
{
    const float* x     = (const float*)d_in[0];
    const float* we_g  = (const float*)d_in[1];
    const float* we_b  = (const float*)d_in[2];
    const float* we_w1 = (const float*)d_in[3];
    const float* we_w2 = (const float*)d_in[4];
    const float* we_b2 = (const float*)d_in[5];
    const float* om_g  = (const float*)d_in[6];
    const float* om_b  = (const float*)d_in[7];
    const float* om_w1 = (const float*)d_in[8];
    const float* om_w2 = (const float*)d_in[9];
    const float* om_b2 = (const float*)d_in[10];

    int N  = in_sizes[0] / 64;     // 2048

    char* ws = (char*)d_ws;
    size_t offV = 0;
    size_t szV  = (size_t)68*65536*2;            // 8.9 MB (65 real + 3 pad slices)
    size_t offQ = offV + szV;
    size_t szQ  = (size_t)N*512*2;               // 2 MB
    size_t offH = offQ + szQ;
    size_t szH  = (size_t)68*N*2;                // 278 KB
    size_t offP = offH + szH;
    size_t szP  = (size_t)17*N*128*2;            // 8.9 MB
    size_t offL = offP + szP;
    size_t szL  = (size_t)N*128*2;
    size_t offW = offL + szL;                    // +128 KB

    unsigned short* Vth = (unsigned short*)(ws + offV);
    unsigned short* Q2h = (unsigned short*)(ws + offQ);
    unsigned short* Htp = (unsigned short*)(ws + offH);
    unsigned short* Par = (unsigned short*)(ws + offP);
    unsigned short* Lnf = (unsigned short*)(ws + offL);
    unsigned short* W1t = (unsigned short*)(ws + offW);
    float* out = (float*)d_out;

    hipLaunchKernelGGL(k_pre,  dim3(264 + N/4), dim3(256), 0, stream,
                       we_w2, we_b2, Vth, om_w1, W1t, x, we_g, we_b, we_w1, Q2h, Htp, N);
    hipLaunchKernelGGL(k_main, dim3(32*17),     dim3(128), 0, stream, Q2h, Vth, Htp, Par, N);
    hipLaunchKernelGGL(k_red,  dim3(N/4),       dim3(128), 0, stream, Par, om_g, om_b, Lnf, N);
    hipLaunchKernelGGL(k_mlp2, dim3(N/64),      dim3(256), 0, stream, Lnf, W1t, om_w2, om_b2, out, N);
}